// Round 1
// baseline (303.550 us; speedup 1.0000x reference)
//
#include <hip/hip_runtime.h>

// filtfilt (order-2 biquad, odd-ext pad=9) over 1024 rows x 32768 fp32.
// Key identity: the reference's per-row scale normalization cancels exactly
// (everything between is linear-homogeneous), so we skip it.
// Parallelization: overlap-and-discard. Poles |z| = sqrt(1/3) ~= 0.577, so a
// zero-state warmup of W steps has error 0.577^W (W=32 -> 2e-8 rel; threshold
// is 8.8e-2). Each thread filters its own chunk after warmup.

#define N_COLS 32768
#define PAD 9
#define LTOT (N_COLS + 2 * PAD)  // 32786
#define SEGS 4
#define S_OUT 8192               // outputs per block (32768/4)
#define WF 32                    // forward warmup (exact at row start)
#define WB 48                    // backward warmup (exact at row end)
#define CF 34                    // forward chunk stride (34 % 32 == 2 -> 2-way LDS alias, free)
#define CB 33                    // backward chunk stride (33 % 32 == 1 -> conflict-free)
#define TPB 256
#define MAXSZ (CF * TPB + WF)    // 8736 floats = 34,944 B LDS -> 4 blocks/CU

__launch_bounds__(TPB, 4)
__global__ void filtfilt_kernel(const float* __restrict__ x,
                                const float* __restrict__ bco,
                                const float* __restrict__ aco,
                                float* __restrict__ out) {
    __shared__ float xs[MAXSZ];
    const int seg = blockIdx.x;
    const int row = blockIdx.y;
    const int tid = threadIdx.x;

    // Load coefficients (cheap, L2-broadcast). DF2T biquad:
    //   y  = B0*x + z0
    //   z0' = z1 + B1*x - A1*y
    //   z1' = B2*x - A2*y
    const float inv_a0 = 1.0f / aco[0];
    const float B0 = bco[0] * inv_a0;
    const float B1 = bco[1] * inv_a0;
    const float B2 = bco[2] * inv_a0;
    const float A1 = aco[1] * inv_a0;
    const float A2 = aco[2] * inv_a0;

    const int G = PAD + seg * S_OUT;            // first output position (xe coords)
    const int A = (G - WF > 0) ? (G - WF) : 0;  // staged range start
    int B = G + CF * TPB;                       // staged/y1 range end
    if (B > LTOT) B = LTOT;
    const int SZ = B - A;

    const float* __restrict__ xrow = x + (size_t)row * N_COLS;

    // ---- phase 1: stage xe[A..B) into LDS (coalesced; edges computed inline)
    for (int u = tid; u < SZ; u += TPB) {
        const int t = A + u;
        float v;
        if (t >= PAD && t < N_COLS + PAD) {
            v = xrow[t - PAD];
        } else if (t < PAD) {
            v = 2.0f * xrow[0] - xrow[PAD - t];                    // left odd ext
        } else {
            v = 2.0f * xrow[N_COLS - 1] - xrow[2 * N_COLS + PAD - 2 - t];  // right odd ext
        }
        xs[u] = v;
    }
    __syncthreads();

    // ---- phase 2: cache forward warmup window in registers (in-place hazard fix)
    const int sf = G + CF * tid;  // forward chunk start
    float xr[WF];
    if (sf < B) {
#pragma unroll
        for (int k = 0; k < WF; ++k) {
            const int t = sf - WF + k;  // for seg>0: t >= A always; seg0: may be < 0
            xr[k] = (t >= A) ? xs[t - A] : 0.0f;  // zeros are a no-op on zero state -> exact
        }
    }
    __syncthreads();

    // ---- phase 3: forward filter; write y1 in place over own chunk
    if (sf < B) {
        float z0 = 0.0f, z1 = 0.0f;
#pragma unroll
        for (int k = 0; k < WF; ++k) {
            const float xv = xr[k];
            const float y = fmaf(B0, xv, z0);
            const float t1 = fmaf(B1, xv, z1);
            z0 = fmaf(-A1, y, t1);
            z1 = fmaf(B2, xv, -A2 * y);
        }
        int tend = sf + CF;
        if (tend > B) tend = B;
        for (int t = sf; t < tend; ++t) {
            const float xv = xs[t - A];
            const float y = fmaf(B0, xv, z0);
            const float t1 = fmaf(B1, xv, z1);
            z0 = fmaf(-A1, y, t1);
            z1 = fmaf(B2, xv, -A2 * y);
            xs[t - A] = y;  // own region only
        }
    }
    __syncthreads();

    // ---- phase 4: backward warmup (reads other threads' y1 -> read-only phase)
    const int sb = G + CB * tid;  // backward chunk start
    float z0 = 0.0f, z1 = 0.0f;
    int e = sb + CB + WB;
    if (e > LTOT) e = LTOT;  // hit true end -> exact zero-state start
    if (sb < B) {
        for (int t = e - 1; t >= sb + CB; --t) {
            const float xv = xs[t - A];
            const float y = fmaf(B0, xv, z0);
            const float t1 = fmaf(B1, xv, z1);
            z0 = fmaf(-A1, y, t1);
            z1 = fmaf(B2, xv, -A2 * y);
        }
    }
    __syncthreads();

    // ---- phase 5: backward main; write final y in place over own chunk
    if (sb < B) {
        int tstart = sb + CB;
        if (tstart > e) tstart = e;
        for (int t = tstart - 1; t >= sb; --t) {
            const float xv = xs[t - A];
            const float y = fmaf(B0, xv, z0);
            const float t1 = fmaf(B1, xv, z1);
            z0 = fmaf(-A1, y, t1);
            z1 = fmaf(B2, xv, -A2 * y);
            xs[t - A] = y;  // own region only
        }
    }
    __syncthreads();

    // ---- phase 6: coalesced write-out of [G, G+S_OUT)
    float* __restrict__ orow = out + (size_t)row * N_COLS + (size_t)seg * S_OUT;
    const int off = G - A;
    for (int v = tid; v < S_OUT; v += TPB) {
        orow[v] = xs[off + v];
    }
}

extern "C" void kernel_launch(void* const* d_in, const int* in_sizes, int n_in,
                              void* d_out, int out_size, void* d_ws, size_t ws_size,
                              hipStream_t stream) {
    const float* x = (const float*)d_in[0];
    const float* b = (const float*)d_in[1];
    const float* a = (const float*)d_in[2];
    float* out = (float*)d_out;
    const int rows = out_size / N_COLS;  // 128*8 = 1024
    dim3 grid(SEGS, rows);
    filtfilt_kernel<<<grid, TPB, 0, stream>>>(x, b, a, out);
}

// Round 2
// 250.344 us; speedup vs baseline: 1.2125x; 1.2125x over previous
//
#include <hip/hip_runtime.h>

// filtfilt (order-2 biquad, odd-ext pad=9) over 1024 rows x 32768 fp32.
// Scale normalization cancels exactly (linear-homogeneous) -> skipped.
// Overlap-and-discard: poles |z| = sqrt(1/3) ~= 0.577; warmup W=24 gives
// rel error 0.577^24 ~ 2e-6 (measured noise floor is 7.8e-3, thr 8.8e-2).
//
// R2 change vs R1: batch all serial-loop LDS traffic into register arrays
// (one unrolled ds_read burst -> recurrence in regs -> one write burst) to
// kill the per-iteration LDS round-trip latency; float4 staging + copyout.

#define N_COLS 32768
#define PAD 9
#define LTOT (N_COLS + 2 * PAD)  // 32786
#define SEGS 4
#define S_OUT 8192               // outputs per block
#define WF 24                    // forward warmup (multiple of 4 for alignment)
#define WB 24                    // backward warmup
#define CF 34                    // fwd chunk (34%32==2 -> free 2-way LDS alias)
#define CB 33                    // bwd chunk (33%32==1 -> conflict-free)
#define TPB 256
#define FB (WF + CF)             // 58 regs forward window
#define KB (CB + WB)             // 57 regs backward window
#define MAXSZ (CF * TPB + WF)    // 8728 floats = 34,912 B -> 4 blocks/CU

__launch_bounds__(TPB, 4)
__global__ void filtfilt_kernel(const float* __restrict__ x,
                                const float* __restrict__ bco,
                                const float* __restrict__ aco,
                                float* __restrict__ out) {
    __shared__ float xs[MAXSZ];
    const int seg = blockIdx.x;
    const int row = blockIdx.y;
    const int tid = threadIdx.x;

    const float inv_a0 = 1.0f / aco[0];
    const float B0 = bco[0] * inv_a0;
    const float B1 = bco[1] * inv_a0;
    const float B2 = bco[2] * inv_a0;
    const float A1 = aco[1] * inv_a0;
    const float A2 = aco[2] * inv_a0;

    const int G = PAD + seg * S_OUT;           // first output position (xe coords)
    int A = G - WF; if (A < 0) A = 0;          // staged range start (seg0: 0)
    int B = G + CF * TPB; if (B > LTOT) B = LTOT;

    const float* __restrict__ xrow = x + (size_t)row * N_COLS;

    // ---- stage xe[A..B) into LDS, float4 (interior counts are all %4==0)
    int gi0 = A - PAD; if (gi0 < 0) gi0 = 0;         // first interior global idx
    int gi1 = B - PAD; if (gi1 > N_COLS) gi1 = N_COLS;
    const int off0 = gi0 + PAD - A;                  // LDS offset of gi0 (0; seg0: 9)
    const int nvec = (gi1 - gi0) >> 2;
    const float4* __restrict__ xg4 = (const float4*)(xrow + gi0);  // gi0 % 4 == 0
    if (off0 == 0) {
        float4* xs4 = (float4*)xs;
        for (int i = tid; i < nvec; i += TPB) xs4[i] = xg4[i];
    } else {  // seg0: LDS misaligned by PAD=9 -> scalar LDS writes
        for (int i = tid; i < nvec; i += TPB) {
            float4 v = xg4[i];
            const int u = off0 + 4 * i;
            xs[u] = v.x; xs[u + 1] = v.y; xs[u + 2] = v.z; xs[u + 3] = v.w;
        }
    }
    for (int g = gi0 + 4 * nvec + tid; g < gi1; g += TPB)  // tail (empty in practice)
        xs[off0 + (g - gi0)] = xrow[g];
    if (tid < PAD) {
        if (A == 0) {  // left odd extension (seg0)
            const int t = tid;
            xs[t] = 2.0f * xrow[0] - xrow[PAD - t];
        }
        if (B == LTOT) {  // right odd extension (seg3)
            const int t = N_COLS + PAD + tid;
            xs[t - A] = 2.0f * xrow[N_COLS - 1] - xrow[2 * N_COLS + PAD - 2 - t];
        }
    }
    __syncthreads();

    // ---- forward: burst-read 58 window floats, recurrence in regs, burst-write 34
    const int sf = G + CF * tid;  // own chunk start; always < B
    float v[FB];
#pragma unroll
    for (int k = 0; k < FB; ++k) {
        const int t = sf - WF + k;
        v[k] = (t >= A) ? xs[t - A] : 0.0f;  // t<A only at seg0: zero keeps exact zero-state
    }
    {
        float z0 = 0.0f, z1 = 0.0f;
#pragma unroll
        for (int k = 0; k < FB; ++k) {
            const float xv = v[k];
            const float y = fmaf(B0, xv, z0);
            z0 = fmaf(-A1, y, fmaf(B1, xv, z1));
            z1 = fmaf(B2, xv, -A2 * y);
            v[k] = y;
        }
    }
    __syncthreads();  // all reads done before in-place overwrite
#pragma unroll
    for (int k = WF; k < FB; ++k) {
        const int t = sf + (k - WF);
        if (t < B) xs[t - A] = v[k];  // only seg3 clamps
    }
    __syncthreads();

    // ---- backward: burst-read 57 y1 floats, reverse recurrence, burst-write 33
    const int sb = G + CB * tid;
    float w[KB];
#pragma unroll
    for (int k = 0; k < KB; ++k) w[k] = xs[sb + k - A];  // <= 8503 < MAXSZ
    {
        float z0 = 0.0f, z1 = 0.0f;
#pragma unroll
        for (int kk = KB - 1; kk >= 0; --kk) {
            const int t = sb + kk;
            if (t < LTOT) {  // seg3 tail lanes skip past-the-end garbage (exact start at LTOT)
                const float xv = w[kk];
                const float y = fmaf(B0, xv, z0);
                z0 = fmaf(-A1, y, fmaf(B1, xv, z1));
                z1 = fmaf(B2, xv, -A2 * y);
                if (kk < CB) w[kk] = y;
            }
        }
    }
    __syncthreads();  // all y1 reads done before overwrite
#pragma unroll
    for (int k = 0; k < CB; ++k) {
        const int t = sb + k;
        if (t < B) xs[t - A] = w[k];
    }
    __syncthreads();

    // ---- coalesced float4 write-out of [G, G+S_OUT)
    float* __restrict__ orow = out + (size_t)row * N_COLS + (size_t)seg * S_OUT;
    const int off = G - A;  // WF (aligned) except seg0 (=9)
    if ((off & 3) == 0) {
        float4* o4 = (float4*)orow;
        const float4* s4 = (const float4*)(xs + off);
        for (int i = tid; i < S_OUT / 4; i += TPB) o4[i] = s4[i];
    } else {
        float4* o4 = (float4*)orow;
        for (int i = tid; i < S_OUT / 4; i += TPB) {
            const int u = off + 4 * i;
            float4 t;
            t.x = xs[u]; t.y = xs[u + 1]; t.z = xs[u + 2]; t.w = xs[u + 3];
            o4[i] = t;
        }
    }
}

extern "C" void kernel_launch(void* const* d_in, const int* in_sizes, int n_in,
                              void* d_out, int out_size, void* d_ws, size_t ws_size,
                              hipStream_t stream) {
    const float* x = (const float*)d_in[0];
    const float* b = (const float*)d_in[1];
    const float* a = (const float*)d_in[2];
    float* out = (float*)d_out;
    const int rows = out_size / N_COLS;  // 128*8 = 1024
    dim3 grid(SEGS, rows);
    filtfilt_kernel<<<grid, TPB, 0, stream>>>(x, b, a, out);
}

// Round 3
// 240.745 us; speedup vs baseline: 1.2609x; 1.0399x over previous
//
#include <hip/hip_runtime.h>

// filtfilt (order-2 biquad, odd-ext pad=9) over 1024 rows x 32768 fp32.
// Scale normalization cancels exactly (linear-homogeneous) -> skipped.
// R3: barrier-free per-WAVE tiles. Each wave owns a private LDS slice and a
// 1088-output segment; intra-wave LDS program-order replaces __syncthreads
// (read bursts strictly precede in-place write bursts in program order, and
// the LDS pipe is in-order per wave). 19.7KB LDS/block -> 8 blocks/CU,
// 32 waves/CU, fully desynchronized. Strides 19/17 (odd) = conflict-free.
// Warmup 16 (err 0.577^16 ~ 1.5e-4); staged zeros make row edges exact.

#define N_COLS 32768
#define PAD 9
#define LTOT  (N_COLS + 2 * PAD)   // 32786
#define OUTEND (N_COLS + PAD)      // 32777: one past last output (xe coords)
#define WF 16
#define WB 16
#define CF 19                      // fwd chunk/lane (odd -> conflict-free)
#define CB 17                      // bwd chunk/lane (odd -> conflict-free)
#define LANES 64
#define P   (CB * LANES)           // 1088 outputs per wave
#define NSEG 31                    // ceil(32768 / 1088)
#define SLOT (WF + CF * LANES)     // 1232 floats = 4928 B per wave
#define WPB 4
#define TPB 256

__launch_bounds__(TPB, 8)
__global__ void filtfilt_kernel(const float* __restrict__ x,
                                const float* __restrict__ bco,
                                const float* __restrict__ aco,
                                float* __restrict__ out,
                                int rows) {
    __shared__ float xs_all[WPB][SLOT];   // 19,712 B
    const int tid = threadIdx.x;
    const int wid = tid >> 6;
    const int lane = tid & 63;
    float* __restrict__ xs = xs_all[wid];

    const int W = blockIdx.x * WPB + wid;  // global wave index
    const int row = W / NSEG;
    const int seg = W - row * NSEG;
    if (row >= rows) return;               // wave-uniform exit, no barriers used

    const float inv_a0 = 1.0f / aco[0];
    const float B0 = bco[0] * inv_a0;
    const float B1 = bco[1] * inv_a0;
    const float B2 = bco[2] * inv_a0;
    const float A1 = aco[1] * inv_a0;
    const float A2 = aco[2] * inv_a0;

    const int G = PAD + seg * P;           // first output position (xe coords)
    const int A = G - WF;                  // slice origin; -7 for seg0
    const float* __restrict__ xrow = x + (size_t)row * N_COLS;

    // ---- stage interior x via float4 (all offsets/counts are %4==0 by design)
    {
        const int g0 = (A - PAD > 0) ? (A - PAD) : 0;
        int g1 = G + CF * LANES; if (g1 > OUTEND) g1 = OUTEND; g1 -= PAD;
        const int off0 = g0 + PAD - A;     // 0 generic; 16 for seg0
        const float4* __restrict__ xg4 = (const float4*)(xrow + g0);
        float4* __restrict__ s4 = (float4*)(xs + off0);
        const int nvec = (g1 - g0) >> 2;
        for (int i = lane; i < nvec; i += LANES) s4[i] = xg4[i];
    }
    // ---- left edge (seg0): offsets [0,16) = t in [-7, 9): zeros then odd-ext
    if (seg == 0) {
        if (lane < WF) {
            const int t = lane - (WF - PAD);   // -7..8
            xs[lane] = (t >= 0) ? (2.0f * xrow[0] - xrow[PAD - t]) : 0.0f;
        }
    }
    // ---- right edge (last seg): odd-ext then zeros (zeros make fwd exact)
    if (seg == NSEG - 1) {
        const float x_last = xrow[N_COLS - 1];
        for (int o = (OUTEND - A) + lane; o < SLOT; o += LANES) {
            const int t = A + o;
            xs[o] = (t < LTOT) ? (2.0f * x_last - xrow[2 * N_COLS + PAD - 2 - t])
                               : 0.0f;
        }
    }

    // ---- forward: burst-read 35-float window, recurrence in regs, write 19 y1
    // intra-wave ordering: these reads (x) precede all y1 writes in program
    // order; cross-lane WAR is safe because the LDS pipe is in-order per wave.
    const int f_off = CF * lane;           // == (sf - WF) - A
    float v[WF + CF];
#pragma unroll
    for (int k = 0; k < WF + CF; ++k) v[k] = xs[f_off + k];
    {
        float z0 = 0.0f, z1 = 0.0f;
#pragma unroll
        for (int k = 0; k < WF + CF; ++k) {
            const float xv = v[k];
            const float y = fmaf(B0, xv, z0);
            z0 = fmaf(-A1, y, fmaf(B1, xv, z1));
            z1 = fmaf(B2, xv, -A2 * y);
            v[k] = y;
        }
    }
#pragma unroll
    for (int k = WF; k < WF + CF; ++k) xs[f_off + k] = v[k];  // y1 over [G, G+1216)

    // ---- re-zero y1 slack past LTOT (last seg) so bwd zero-state is exact
    if (seg == NSEG - 1) {
        for (int o = (LTOT - A) + lane; o < SLOT; o += LANES) xs[o] = 0.0f;
    }

    // ---- backward: burst-read 33 y1 (pre-overwrite values, by program order),
    // reverse recurrence, write 17 final outputs in place
    const int b_off = CB * lane + WF;      // == sb - A
    float w[CB + WB];
#pragma unroll
    for (int k = 0; k < CB + WB; ++k) w[k] = xs[b_off + k];
    {
        float z0 = 0.0f, z1 = 0.0f;
#pragma unroll
        for (int k = CB + WB - 1; k >= 0; --k) {
            const float xv = w[k];
            const float y = fmaf(B0, xv, z0);
            z0 = fmaf(-A1, y, fmaf(B1, xv, z1));
            z1 = fmaf(B2, xv, -A2 * y);
            if (k < CB) w[k] = y;
        }
    }
#pragma unroll
    for (int k = 0; k < CB; ++k) xs[b_off + k] = w[k];

    // ---- coalesced float4 copy-out of [G, G+nout)
    int nout = OUTEND - G; if (nout > P) nout = P;   // 1088, or 128 on last seg
    float* __restrict__ orow = out + (size_t)row * N_COLS + (G - PAD);
    const float4* __restrict__ s4 = (const float4*)(xs + WF);  // (G-A)==16
    float4* __restrict__ o4 = (float4*)orow;
    const int nv = nout >> 2;
    for (int i = lane; i < nv; i += LANES) o4[i] = s4[i];
}

extern "C" void kernel_launch(void* const* d_in, const int* in_sizes, int n_in,
                              void* d_out, int out_size, void* d_ws, size_t ws_size,
                              hipStream_t stream) {
    const float* x = (const float*)d_in[0];
    const float* b = (const float*)d_in[1];
    const float* a = (const float*)d_in[2];
    float* out = (float*)d_out;
    const int rows = out_size / N_COLS;                // 1024
    const int total_waves = rows * NSEG;               // 31744
    const int blocks = (total_waves + WPB - 1) / WPB;  // 7936
    filtfilt_kernel<<<blocks, TPB, 0, stream>>>(x, b, a, out, rows);
}